// Round 4
// baseline (2806.769 us; speedup 1.0000x reference)
//
#include <hip/hip_runtime.h>

#define EMD 0.77880078307140486824  // exp(-1/4), double
#define ESD 0.36787944117144232160  // exp(-1), double

// t-chunked f64 pipeline: 8 chunks of TC=64 timesteps.
// All intermediates f64; recurrences exactly sequential with carried state.

// ---------------------------------------------------------------------------
// GEMM1 chunk: per batch b, 64 f-rows x 64 t-cols, K=784.
// MODE 0: lv rows (500..999) -> G = exp(0.5*relu(acc+bias))        -> OUTB
// MODE 1: mu rows (0..499)   -> sample = relu(acc+bias) + eps*G    -> OUTB
// OUTB layout: (b, f, tt) chunk-local, index (b*500+f)*64 + tt.
// ---------------------------------------------------------------------------
template <int MODE>
__global__ __launch_bounds__(256) void g1_chunk(
    const float* __restrict__ X,    // (64,784,512)
    const float* __restrict__ W1,   // (1000,784)
    const float* __restrict__ B1,   // (1000)
    const float* __restrict__ EPS,  // (64,500,512)
    const double* __restrict__ G,   // (b,f,tt) chunk (MODE 1)
    double* __restrict__ OUTB,      // (b,f,tt) chunk
    int t0)
{
    const int b  = blockIdx.z;
    const int m0 = blockIdx.y * 64;
    const int rowbase = (MODE == 0) ? 500 : 0;

    __shared__ double As[16][64];  // [k][f]
    __shared__ double Bs[16][64];  // [k][tt]

    const int tid = threadIdx.x;
    const int tx = tid & 15;       // tt dir
    const int ty = tid >> 4;       // f dir

    double acc[4][4] = {};

    for (int k0 = 0; k0 < 784; k0 += 16) {
        {
            int m  = tid >> 2;
            int kk = (tid & 3) * 4;
            int row = m0 + m;
            row = row > 499 ? 499 : row;
            row += rowbase;
            const float4 av = *(const float4*)&W1[(size_t)row * 784 + k0 + kk];
            As[kk + 0][m] = (double)av.x;
            As[kk + 1][m] = (double)av.y;
            As[kk + 2][m] = (double)av.z;
            As[kk + 3][m] = (double)av.w;
        }
        {
            int bk = tid >> 4;
            int bt = (tid & 15) * 4;
            const float4 bv = *(const float4*)&X[((size_t)b * 784 + k0 + bk) * 512 + t0 + bt];
            Bs[bk][bt + 0] = (double)bv.x;
            Bs[bk][bt + 1] = (double)bv.y;
            Bs[bk][bt + 2] = (double)bv.z;
            Bs[bk][bt + 3] = (double)bv.w;
        }
        __syncthreads();
        #pragma unroll
        for (int k = 0; k < 16; ++k) {
            double ar[4], br[4];
            #pragma unroll
            for (int c = 0; c < 4; ++c) { ar[c] = As[k][ty * 4 + c]; br[c] = Bs[k][tx * 4 + c]; }
            #pragma unroll
            for (int i = 0; i < 4; ++i)
                #pragma unroll
                for (int j = 0; j < 4; ++j)
                    acc[i][j] = fma(ar[i], br[j], acc[i][j]);
        }
        __syncthreads();
    }

    const int tcol = tx * 4;
    #pragma unroll
    for (int i = 0; i < 4; ++i) {
        const int fo = m0 + ty * 4 + i;
        if (fo >= 500) continue;
        const size_t oidx = ((size_t)b * 500 + fo) * 64 + tcol;
        if (MODE == 0) {
            const double bias = (double)B1[500 + fo];
            #pragma unroll
            for (int j = 0; j < 4; ++j) {
                const double z = fmax(acc[i][j] + bias, 0.0);
                OUTB[oidx + j] = exp(0.5 * z);
            }
        } else {
            const double bias = (double)B1[fo];
            const float4 e = *(const float4*)&EPS[((size_t)b * 500 + fo) * 512 + t0 + tcol];
            const float er[4] = {e.x, e.y, e.z, e.w};
            #pragma unroll
            for (int j = 0; j < 4; ++j) {
                const double mu = fmax(acc[i][j] + bias, 0.0);
                OUTB[oidx + j] = mu + (double)er[j] * G[oidx + j];
            }
        }
    }
}

// ---------------------------------------------------------------------------
// IIR2 chunk with transpose: IN (row, tt) -> OUT (tt, row), row = b*500+f.
// Exactly sequential in t; carries (m,s) per row across chunks.
// ---------------------------------------------------------------------------
__global__ __launch_bounds__(256) void iir2T_chunk(
    const double* __restrict__ IN, double* __restrict__ OUT,
    double* __restrict__ stM, double* __restrict__ stS, int first)
{
    __shared__ double tile[64][67];
    const int tid = threadIdx.x;
    const int r0 = blockIdx.x * 64;

    #pragma unroll
    for (int q = 0; q < 8; ++q) {
        const int e2 = q * 256 + tid;      // f64x2 index
        const int r = e2 >> 5;             // 32 pairs per row
        const int c = (e2 & 31) * 2;
        const double2 v = *(const double2*)&IN[(size_t)(r0 + r) * 64 + c];
        tile[r][c] = v.x;
        tile[r][c + 1] = v.y;
    }
    __syncthreads();
    if (tid < 64) {
        const int r = r0 + tid;
        double m = first ? 0.0 : stM[r];
        double s = first ? 0.0 : stS[r];
        #pragma unroll
        for (int c = 0; c < 64; ++c) {
            const double x = tile[tid][c];
            m = EMD * m + x;
            s = ESD * s + x;
            tile[tid][c] = m - s;
        }
        stM[r] = m;
        stS[r] = s;
    }
    __syncthreads();
    #pragma unroll
    for (int q = 0; q < 16; ++q) {
        const int r = tid & 63;
        const int tt = (tid >> 6) + q * 4;
        OUT[(size_t)tt * 32000 + r0 + r] = tile[r][tt];
    }
}

// ---------------------------------------------------------------------------
// GEMM2 chunk: C[R][o] = sum_i A[R][i]*W2[o][i] + B2[o]; R = tt*64+b (4096).
// ---------------------------------------------------------------------------
__global__ __launch_bounds__(256) void g2_chunk(
    const double* __restrict__ A,   // (4096,500)
    const float* __restrict__ W2,   // (500,500)
    const float* __restrict__ B2,   // (500)
    double* __restrict__ C)         // (4096,500)
{
    const int o0 = blockIdx.x * 64;
    const int R0 = blockIdx.y * 64;

    __shared__ double As[16][64];   // [k][R]
    __shared__ double Bs[16][64];   // [k][o]

    const int tid = threadIdx.x;
    const int tx = tid & 15;        // o dir
    const int ty = tid >> 4;        // R dir

    double acc[4][4] = {};

    for (int k0 = 0; k0 < 512; k0 += 16) {
        {
            const int m  = tid >> 2;
            const int kk = (tid & 3) * 4;
            const double* arow = A + (size_t)(R0 + m) * 500;
            #pragma unroll
            for (int c = 0; c < 4; ++c) {
                const int k = k0 + kk + c;
                As[kk + c][m] = (k < 500) ? arow[k] : 0.0;
            }
        }
        {
            const int oo = tid >> 2;
            const int ic = (tid & 3) * 4;
            int oc = o0 + oo;
            oc = oc > 499 ? 499 : oc;
            const float* wrow = W2 + (size_t)oc * 500;
            #pragma unroll
            for (int c = 0; c < 4; ++c) {
                const int k = k0 + ic + c;
                Bs[ic + c][oo] = (k < 500) ? (double)wrow[k] : 0.0;
            }
        }
        __syncthreads();
        #pragma unroll
        for (int k = 0; k < 16; ++k) {
            double ar[4], br[4];
            #pragma unroll
            for (int c = 0; c < 4; ++c) { ar[c] = As[k][ty * 4 + c]; br[c] = Bs[k][tx * 4 + c]; }
            #pragma unroll
            for (int i = 0; i < 4; ++i)
                #pragma unroll
                for (int j = 0; j < 4; ++j)
                    acc[i][j] = fma(ar[i], br[j], acc[i][j]);
        }
        __syncthreads();
    }

    const int ocol = o0 + tx * 4;
    #pragma unroll
    for (int i = 0; i < 4; ++i) {
        const int R = R0 + ty * 4 + i;
        #pragma unroll
        for (int j = 0; j < 4; ++j) {
            const int o = ocol + j;
            if (o < 500) C[(size_t)R * 500 + o] = acc[i][j] + (double)B2[o];
        }
    }
}

// ---------------------------------------------------------------------------
// LIF2 + IIR3 fused, in-place on (tt, 32000); carries (v, sp, m, s).
// ---------------------------------------------------------------------------
__global__ __launch_bounds__(256) void lif2iir3_chunk(
    double* __restrict__ WX,
    double* __restrict__ stV, double* __restrict__ stSp,
    double* __restrict__ stM, double* __restrict__ stS, int first)
{
    const int idx = blockIdx.x * 256 + threadIdx.x;
    if (idx >= 32000) return;
    double v, sp, m, s;
    if (first) { v = 0.0; sp = 0.0; m = 0.0; s = 0.0; }
    else { v = stV[idx]; sp = stSp[idx]; m = stM[idx]; s = stS[idx]; }
    for (int tt = 0; tt < 64; ++tt) {
        const double cur = WX[(size_t)tt * 32000 + idx];
        v = EMD * v * (1.0 - sp) + cur;
        sp = (v >= 1.0) ? 1.0 : 0.0;
        m = EMD * m + sp;
        s = ESD * s + sp;
        WX[(size_t)tt * 32000 + idx] = m - s;
    }
    stV[idx] = v; stSp[idx] = sp; stM[idx] = m; stS[idx] = s;
}

// ---------------------------------------------------------------------------
// GEMM3 chunk: WX3[R*10+o] = sum_i A3[R][i]*W3[o][i] + B3[o]; R<4096.
// ---------------------------------------------------------------------------
__global__ __launch_bounds__(256) void g3_chunk(
    const double* __restrict__ A3,  // (4096,500)
    const float* __restrict__ W3,   // (10,500)
    const float* __restrict__ B3,   // (10)
    double* __restrict__ WX3)       // (4096,10)
{
    __shared__ float w3s[5000];
    for (int i = threadIdx.x; i < 5000; i += 256) w3s[i] = W3[i];
    __syncthreads();
    const int id = blockIdx.x * 256 + threadIdx.x;
    if (id >= 40960) return;
    const int o = id % 10;
    const int R = id / 10;
    const double* ap = A3 + (size_t)R * 500;
    const float* wp = w3s + o * 500;
    double acc = (double)B3[o];
    for (int i = 0; i < 500; ++i)
        acc = fma(ap[i], (double)wp[i], acc);
    WX3[id] = acc;
}

// ---------------------------------------------------------------------------
// LIF3 chunk: (tt*640+idx) -> OUT[idx*512 + t0+tt]; carries (v, sp).
// ---------------------------------------------------------------------------
__global__ __launch_bounds__(256) void lif3_chunk(
    const double* __restrict__ WX3, float* __restrict__ OUT,
    double* __restrict__ stV, double* __restrict__ stSp, int first, int t0)
{
    const int idx = blockIdx.x * 256 + threadIdx.x;
    if (idx >= 640) return;
    double v = first ? 0.0 : stV[idx];
    double sp = first ? 0.0 : stSp[idx];
    for (int tt = 0; tt < 64; ++tt) {
        const double cur = WX3[(size_t)tt * 640 + idx];
        v = EMD * v * (1.0 - sp) + cur;
        sp = (v >= 1.0) ? 1.0 : 0.0;
        OUT[(size_t)idx * 512 + t0 + tt] = (float)sp;
    }
    stV[idx] = v; stSp[idx] = sp;
}

__global__ void sent_kernel(float* __restrict__ OUT, float v) { OUT[0] = v; }

// ---------------------------------------------------------------------------
extern "C" void kernel_launch(void* const* d_in, const int* in_sizes, int n_in,
                              void* d_out, int out_size, void* d_ws, size_t ws_size,
                              hipStream_t stream)
{
    float* OUT = (float*)d_out;

    const int expect[8] = {25690112, 16384000, 784000, 1000, 250000, 500, 5000, 10};
    int bad = -1;
    if (n_in != 8) bad = 0;
    else {
        for (int k = 0; k < 8; ++k)
            if (in_sizes[k] != expect[k]) { bad = 1 + k; break; }
        if (bad < 0 && out_size != 327680) bad = 9;
        if (bad < 0 && ws_size < (size_t)68000000) bad = 10;
    }
    if (bad >= 0) {
        sent_kernel<<<1, 1, 0, stream>>>(OUT, 4100.0f + bad);
        return;
    }

    const float* X   = (const float*)d_in[0];
    const float* EPS = (const float*)d_in[1];
    const float* W1  = (const float*)d_in[2];
    const float* B1  = (const float*)d_in[3];
    const float* W2  = (const float*)d_in[4];
    const float* B2  = (const float*)d_in[5];
    const float* W3  = (const float*)d_in[6];
    const float* B3  = (const float*)d_in[7];

    double* ws = (double*)d_ws;
    double* bufG  = ws;              // 2,048,000 doubles (b,f,tt)
    double* buf1  = ws + 2048000;    // sample (b,f,tt)
    double* buf1T = ws + 4096000;    // a2 (tt,b,f)
    double* buf2  = ws + 6144000;    // wx2/a3 (tt,b,o)
    double* buf4  = ws + 8192000;    // wx3 (R,10): 40,960
    double* stM2  = ws + 8240000;    // 32,000 each
    double* stS2  = ws + 8280000;
    double* stV2  = ws + 8320000;
    double* stSp2 = ws + 8360000;
    double* stM3  = ws + 8400000;
    double* stS3  = ws + 8440000;
    double* stV3  = ws + 8480000;    // 640 each
    double* stSp3 = ws + 8481000;

    for (int tc = 0; tc < 8; ++tc) {
        const int t0 = tc * 64;
        const int first = (tc == 0) ? 1 : 0;
        g1_chunk<0><<<dim3(1, 8, 64), 256, 0, stream>>>(X, W1, B1, EPS, nullptr, bufG, t0);
        g1_chunk<1><<<dim3(1, 8, 64), 256, 0, stream>>>(X, W1, B1, EPS, bufG, buf1, t0);
        iir2T_chunk<<<500, 256, 0, stream>>>(buf1, buf1T, stM2, stS2, first);
        g2_chunk<<<dim3(8, 64), 256, 0, stream>>>(buf1T, W2, B2, buf2);
        lif2iir3_chunk<<<125, 256, 0, stream>>>(buf2, stV2, stSp2, stM3, stS3, first);
        g3_chunk<<<160, 256, 0, stream>>>(buf2, W3, B3, buf4);
        lif3_chunk<<<3, 256, 0, stream>>>(buf4, OUT, stV3, stSp3, first, t0);
    }
}

// Round 5
// 2163.395 us; speedup vs baseline: 1.2974x; 1.2974x over previous
//
#include <hip/hip_runtime.h>

#define EMD 0.77880078307140486824  // exp(-1/4)
#define ESD 0.36787944117144232160  // exp(-1)
#define TC 128                      // timesteps per chunk (4 chunks of 512)

// ---------------------------------------------------------------------------
// g1_fused: per (b, f-tile, t-tile): both mu row f and lv row 500+f, K=784.
// sample = relu(mu)+eps*exp(0.5*relu(lv)) -> SAMP (b,f,tt) chunk-local.
// Conflict-free micro-tile: rows/cols {2q,2q+1,2q+32,2q+33}.
// FMA order identical to round-4 (k ascending, single accumulator).
// ---------------------------------------------------------------------------
__global__ __launch_bounds__(256) void g1_fused(
    const float* __restrict__ X,    // (64,784,512)
    const float* __restrict__ W1,   // (1000,784)
    const float* __restrict__ B1,   // (1000)
    const float* __restrict__ EPS,  // (64,500,512)
    double* __restrict__ SAMP,      // (64,500,TC)
    int t0)
{
    const int b   = blockIdx.z;
    const int m0  = blockIdx.y * 64;
    const int tt0 = blockIdx.x * 64;      // 0 or 64 within chunk
    const int tg  = t0 + tt0;             // global t tile start

    __shared__ double Am[16][65];
    __shared__ double Al[16][65];
    __shared__ double Bs[16][65];

    const int tid = threadIdx.x;
    const int tx = tid & 15;
    const int ty = tid >> 4;

    double am[4][4] = {};
    double al[4][4] = {};

    for (int k0 = 0; k0 < 784; k0 += 16) {
        {
            const int m  = tid >> 2;
            const int kk = (tid & 3) * 4;
            int f = m0 + m; if (f > 499) f = 499;
            const float4 aw = *(const float4*)&W1[(size_t)f * 784 + k0 + kk];
            Am[kk+0][m] = (double)aw.x; Am[kk+1][m] = (double)aw.y;
            Am[kk+2][m] = (double)aw.z; Am[kk+3][m] = (double)aw.w;
            const float4 lw = *(const float4*)&W1[(size_t)(500 + f) * 784 + k0 + kk];
            Al[kk+0][m] = (double)lw.x; Al[kk+1][m] = (double)lw.y;
            Al[kk+2][m] = (double)lw.z; Al[kk+3][m] = (double)lw.w;
        }
        {
            const int bk = tid >> 4;          // 0..15
            const int bt = (tid & 15) * 4;
            const float4 xv = *(const float4*)&X[((size_t)b * 784 + k0 + bk) * 512 + tg + bt];
            Bs[bk][bt+0] = (double)xv.x; Bs[bk][bt+1] = (double)xv.y;
            Bs[bk][bt+2] = (double)xv.z; Bs[bk][bt+3] = (double)xv.w;
        }
        __syncthreads();
        #pragma unroll
        for (int k = 0; k < 16; ++k) {
            const double ar[4] = {Am[k][2*ty], Am[k][2*ty+1], Am[k][2*ty+32], Am[k][2*ty+33]};
            const double lr[4] = {Al[k][2*ty], Al[k][2*ty+1], Al[k][2*ty+32], Al[k][2*ty+33]};
            const double br[4] = {Bs[k][2*tx], Bs[k][2*tx+1], Bs[k][2*tx+32], Bs[k][2*tx+33]};
            #pragma unroll
            for (int i = 0; i < 4; ++i)
                #pragma unroll
                for (int j = 0; j < 4; ++j) {
                    am[i][j] = fma(ar[i], br[j], am[i][j]);
                    al[i][j] = fma(lr[i], br[j], al[i][j]);
                }
        }
        __syncthreads();
    }

    const int rows[4] = {2*ty, 2*ty+1, 2*ty+32, 2*ty+33};
    const int cols[4] = {2*tx, 2*tx+1, 2*tx+32, 2*tx+33};
    #pragma unroll
    for (int i = 0; i < 4; ++i) {
        const int f = m0 + rows[i];
        if (f >= 500) continue;
        const double bm = (double)B1[f];
        const double bl = (double)B1[500 + f];
        #pragma unroll
        for (int j = 0; j < 4; ++j) {
            const int tl = tt0 + cols[j];     // 0..TC-1
            const double mu = fmax(am[i][j] + bm, 0.0);
            const double lv = fmax(al[i][j] + bl, 0.0);
            const double e  = (double)EPS[((size_t)b * 500 + f) * 512 + t0 + tl];
            SAMP[((size_t)b * 500 + f) * TC + tl] = mu + e * exp(0.5 * lv);
        }
    }
}

// ---------------------------------------------------------------------------
// iir2: exact sequential dual-exp, in-place on (32000 rows, TC). 64 rows per
// block staged through LDS in 64-col sub-chunks; (m,s) carried across chunks.
// ---------------------------------------------------------------------------
__global__ __launch_bounds__(256) void iir2_chunk(
    double* __restrict__ A,
    double* __restrict__ stM, double* __restrict__ stS, int first)
{
    __shared__ double tile[64][65];
    const int tid = threadIdx.x;
    const int r0 = blockIdx.x * 64;
    double m = 0.0, s = 0.0;
    if (tid < 64 && !first) { m = stM[r0 + tid]; s = stS[r0 + tid]; }

    for (int sub = 0; sub < TC / 64; ++sub) {
        #pragma unroll
        for (int q = 0; q < 8; ++q) {
            const int e2 = q * 256 + tid;
            const int r = e2 >> 5;
            const int c = (e2 & 31) * 2;
            const double2 v = *(const double2*)&A[(size_t)(r0 + r) * TC + sub * 64 + c];
            tile[r][c] = v.x; tile[r][c + 1] = v.y;
        }
        __syncthreads();
        if (tid < 64) {
            #pragma unroll
            for (int c = 0; c < 64; ++c) {
                const double x = tile[tid][c];
                m = EMD * m + x;
                s = ESD * s + x;
                tile[tid][c] = m - s;
            }
        }
        __syncthreads();
        #pragma unroll
        for (int q = 0; q < 8; ++q) {
            const int e2 = q * 256 + tid;
            const int r = e2 >> 5;
            const int c = (e2 & 31) * 2;
            double2 v; v.x = tile[r][c]; v.y = tile[r][c + 1];
            *(double2*)&A[(size_t)(r0 + r) * TC + sub * 64 + c] = v;
        }
        __syncthreads();
    }
    if (tid < 64) { stM[r0 + tid] = m; stS[r0 + tid] = s; }
}

// ---------------------------------------------------------------------------
// g2: wx2[tl,b,o] = sum_f a2[b,f,tl]*W2[o,f] + B2[o]; K=500 padded to 512.
// Same conflict-free micro-tile. FMA order identical to round-4.
// ---------------------------------------------------------------------------
__global__ __launch_bounds__(256) void g2_chunk(
    const double* __restrict__ A2,  // (64,500,TC)
    const float* __restrict__ W2,   // (500,500)
    const float* __restrict__ B2,   // (500)
    double* __restrict__ WX2)       // (TC,64,500)
{
    const int b   = blockIdx.z;
    const int o0  = blockIdx.y * 64;
    const int tt0 = blockIdx.x * 64;

    __shared__ double At[16][65];
    __shared__ double Wo[16][65];

    const int tid = threadIdx.x;
    const int tx = tid & 15;   // o dir
    const int ty = tid >> 4;   // tt dir

    double acc[4][4] = {};

    for (int k0 = 0; k0 < 512; k0 += 16) {
        {
            const int kk = tid >> 4;
            const int t4 = (tid & 15) * 4;
            const int f = k0 + kk;
            if (f < 500) {
                const double2 v0 = *(const double2*)&A2[((size_t)b * 500 + f) * TC + tt0 + t4];
                const double2 v1 = *(const double2*)&A2[((size_t)b * 500 + f) * TC + tt0 + t4 + 2];
                At[kk][t4+0] = v0.x; At[kk][t4+1] = v0.y;
                At[kk][t4+2] = v1.x; At[kk][t4+3] = v1.y;
            } else {
                At[kk][t4+0] = 0.0; At[kk][t4+1] = 0.0;
                At[kk][t4+2] = 0.0; At[kk][t4+3] = 0.0;
            }
        }
        {
            const int oo = tid >> 2;
            const int fc = (tid & 3) * 4;
            int o = o0 + oo; if (o > 499) o = 499;
            const int f = k0 + fc;
            if (f + 3 < 500) {
                const float4 w = *(const float4*)&W2[(size_t)o * 500 + f];
                Wo[fc+0][oo] = (double)w.x; Wo[fc+1][oo] = (double)w.y;
                Wo[fc+2][oo] = (double)w.z; Wo[fc+3][oo] = (double)w.w;
            } else {
                #pragma unroll
                for (int c = 0; c < 4; ++c)
                    Wo[fc+c][oo] = (f + c < 500) ? (double)W2[(size_t)o * 500 + f + c] : 0.0;
            }
        }
        __syncthreads();
        #pragma unroll
        for (int k = 0; k < 16; ++k) {
            const double ar[4] = {At[k][2*ty], At[k][2*ty+1], At[k][2*ty+32], At[k][2*ty+33]};
            const double br[4] = {Wo[k][2*tx], Wo[k][2*tx+1], Wo[k][2*tx+32], Wo[k][2*tx+33]};
            #pragma unroll
            for (int i = 0; i < 4; ++i)
                #pragma unroll
                for (int j = 0; j < 4; ++j)
                    acc[i][j] = fma(ar[i], br[j], acc[i][j]);
        }
        __syncthreads();
    }

    const int rows[4] = {2*ty, 2*ty+1, 2*ty+32, 2*ty+33};
    const int cols[4] = {2*tx, 2*tx+1, 2*tx+32, 2*tx+33};
    #pragma unroll
    for (int i = 0; i < 4; ++i) {
        const int tl = tt0 + rows[i];
        #pragma unroll
        for (int j = 0; j < 4; ++j) {
            const int o = o0 + cols[j];
            if (o < 500)
                WX2[((size_t)tl * 64 + b) * 500 + o] = acc[i][j] + (double)B2[o];
        }
    }
}

// ---------------------------------------------------------------------------
// LIF2 + IIR3 fused, in-place on (TC, 32000); carries (v, sp, m, s).
// ---------------------------------------------------------------------------
__global__ __launch_bounds__(256) void lif2iir3_chunk(
    double* __restrict__ WX,
    double* __restrict__ stV, double* __restrict__ stSp,
    double* __restrict__ stM, double* __restrict__ stS, int first)
{
    const int idx = blockIdx.x * 256 + threadIdx.x;
    if (idx >= 32000) return;
    double v, sp, m, s;
    if (first) { v = 0.0; sp = 0.0; m = 0.0; s = 0.0; }
    else { v = stV[idx]; sp = stSp[idx]; m = stM[idx]; s = stS[idx]; }
    for (int tt = 0; tt < TC; ++tt) {
        const double cur = WX[(size_t)tt * 32000 + idx];
        v = EMD * v * (1.0 - sp) + cur;
        sp = (v >= 1.0) ? 1.0 : 0.0;
        m = EMD * m + sp;
        s = ESD * s + sp;
        WX[(size_t)tt * 32000 + idx] = m - s;
    }
    stV[idx] = v; stSp[idx] = sp; stM[idx] = m; stS[idx] = s;
}

// ---------------------------------------------------------------------------
// g3: WX3[R*10+o] = sum_i A3[R][i]*W3[o][i] + B3[o]; R = tl*64+b < 64*TC.
// ---------------------------------------------------------------------------
__global__ __launch_bounds__(256) void g3_chunk(
    const double* __restrict__ A3,  // (64*TC, 500)
    const float* __restrict__ W3,   // (10,500)
    const float* __restrict__ B3,   // (10)
    double* __restrict__ WX3)       // (64*TC, 10)
{
    __shared__ float w3s[5000];
    for (int i = threadIdx.x; i < 5000; i += 256) w3s[i] = W3[i];
    __syncthreads();
    const int id = blockIdx.x * 256 + threadIdx.x;
    if (id >= 64 * TC * 10) return;
    const int o = id % 10;
    const int R = id / 10;
    const double* ap = A3 + (size_t)R * 500;
    const float* wp = w3s + o * 500;
    double acc = (double)B3[o];
    for (int i = 0; i < 500; ++i)
        acc = fma(ap[i], (double)wp[i], acc);
    WX3[id] = acc;
}

// ---------------------------------------------------------------------------
// lif3: (tt*640+idx) -> OUT[idx*512 + t0+tt]; carries (v, sp).
// ---------------------------------------------------------------------------
__global__ __launch_bounds__(256) void lif3_chunk(
    const double* __restrict__ WX3, float* __restrict__ OUT,
    double* __restrict__ stV, double* __restrict__ stSp, int first, int t0)
{
    const int idx = blockIdx.x * 256 + threadIdx.x;
    if (idx >= 640) return;
    double v = first ? 0.0 : stV[idx];
    double sp = first ? 0.0 : stSp[idx];
    for (int tt = 0; tt < TC; ++tt) {
        const double cur = WX3[(size_t)tt * 640 + idx];
        v = EMD * v * (1.0 - sp) + cur;
        sp = (v >= 1.0) ? 1.0 : 0.0;
        OUT[(size_t)idx * 512 + t0 + tt] = (float)sp;
    }
    stV[idx] = v; stSp[idx] = sp;
}

__global__ void sent_kernel(float* __restrict__ OUT, float v) { OUT[0] = v; }

// ---------------------------------------------------------------------------
extern "C" void kernel_launch(void* const* d_in, const int* in_sizes, int n_in,
                              void* d_out, int out_size, void* d_ws, size_t ws_size,
                              hipStream_t stream)
{
    float* OUT = (float*)d_out;

    const int expect[8] = {25690112, 16384000, 784000, 1000, 250000, 500, 5000, 10};
    int bad = -1;
    if (n_in != 8) bad = 0;
    else {
        for (int k = 0; k < 8; ++k)
            if (in_sizes[k] != expect[k]) { bad = 1 + k; break; }
        if (bad < 0 && out_size != 327680) bad = 9;
        if (bad < 0 && ws_size < (size_t)68000000) bad = 10;
    }
    if (bad >= 0) {
        sent_kernel<<<1, 1, 0, stream>>>(OUT, 4100.0f + bad);
        return;
    }

    const float* X   = (const float*)d_in[0];
    const float* EPS = (const float*)d_in[1];
    const float* W1  = (const float*)d_in[2];
    const float* B1  = (const float*)d_in[3];
    const float* W2  = (const float*)d_in[4];
    const float* B2  = (const float*)d_in[5];
    const float* W3  = (const float*)d_in[6];
    const float* B3  = (const float*)d_in[7];

    double* ws = (double*)d_ws;
    double* buf1  = ws;              // (64,500,TC)  4,096,000
    double* buf2  = ws + 4096000;    // (TC,64,500)  4,096,000
    double* buf4  = ws + 8192000;    // (64*TC,10)      81,920
    double* stM2  = ws + 8280000;
    double* stS2  = ws + 8312000;
    double* stV2  = ws + 8344000;
    double* stSp2 = ws + 8376000;
    double* stM3  = ws + 8408000;
    double* stS3  = ws + 8440000;
    double* stV3  = ws + 8472000;
    double* stSp3 = ws + 8473000;

    for (int tc = 0; tc < 512 / TC; ++tc) {
        const int t0 = tc * TC;
        const int first = (tc == 0) ? 1 : 0;
        g1_fused<<<dim3(TC / 64, 8, 64), 256, 0, stream>>>(X, W1, B1, EPS, buf1, t0);
        iir2_chunk<<<500, 256, 0, stream>>>(buf1, stM2, stS2, first);
        g2_chunk<<<dim3(TC / 64, 8, 64), 256, 0, stream>>>(buf1, W2, B2, buf2);
        lif2iir3_chunk<<<125, 256, 0, stream>>>(buf2, stV2, stSp2, stM3, stS3, first);
        g3_chunk<<<320, 256, 0, stream>>>(buf2, W3, B3, buf4);
        lif3_chunk<<<3, 256, 0, stream>>>(buf4, OUT, stV3, stSp3, first, t0);
    }
}

// Round 6
// 1781.424 us; speedup vs baseline: 1.5756x; 1.2144x over previous
//
#include <hip/hip_runtime.h>

#define EMD 0.77880078307140486824  // exp(-1/4)
#define ESD 0.36787944117144232160  // exp(-1)
#define TC 128                      // timesteps per chunk (4 chunks of 512)

// ---------------------------------------------------------------------------
// g1_fused: per (b, f-tile): mu row f and lv row 500+f, K=784, t-tile = 128.
// Micro-tile 4m x 8t; block tile 64m x 128t; acc order: k ascending, single
// FMA chain per output (bit-identical to round 5).
// sample = relu(mu)+eps*exp(0.5*relu(lv)) -> SAMP (b,f,tt) chunk-local.
// ---------------------------------------------------------------------------
__global__ __launch_bounds__(256) void g1_fused(
    const float* __restrict__ X,    // (64,784,512)
    const float* __restrict__ W1,   // (1000,784)
    const float* __restrict__ B1,   // (1000)
    const float* __restrict__ EPS,  // (64,500,512)
    double* __restrict__ SAMP,      // (64,500,TC)
    int t0)
{
    const int b  = blockIdx.z;
    const int m0 = blockIdx.y * 64;

    __shared__ double Am[16][66];
    __shared__ double Al[16][66];
    __shared__ double Bs[16][130];

    const int tid = threadIdx.x;
    const int tx = tid & 15;       // t dir: cols {2tx,2tx+1}+{0,32,64,96}
    const int ty = tid >> 4;       // m dir: rows {2ty,2ty+1,2ty+32,2ty+33}

    double am[4][8] = {};
    double al[4][8] = {};

    for (int k0 = 0; k0 < 784; k0 += 16) {
        {   // stage A (mu + lv): 64 m x 16 k
            const int m  = tid >> 2;
            const int kk = (tid & 3) * 4;
            int f = m0 + m; if (f > 499) f = 499;
            const float4 aw = *(const float4*)&W1[(size_t)f * 784 + k0 + kk];
            Am[kk+0][m] = (double)aw.x; Am[kk+1][m] = (double)aw.y;
            Am[kk+2][m] = (double)aw.z; Am[kk+3][m] = (double)aw.w;
            const float4 lw = *(const float4*)&W1[(size_t)(500 + f) * 784 + k0 + kk];
            Al[kk+0][m] = (double)lw.x; Al[kk+1][m] = (double)lw.y;
            Al[kk+2][m] = (double)lw.z; Al[kk+3][m] = (double)lw.w;
        }
        {   // stage B: 16 k x 128 t
            const int bk = tid >> 4;
            const int bt = (tid & 15) * 8;
            const float* xp = &X[((size_t)b * 784 + k0 + bk) * 512 + t0 + bt];
            const float4 x0 = *(const float4*)xp;
            const float4 x1 = *(const float4*)(xp + 4);
            Bs[bk][bt+0] = (double)x0.x; Bs[bk][bt+1] = (double)x0.y;
            Bs[bk][bt+2] = (double)x0.z; Bs[bk][bt+3] = (double)x0.w;
            Bs[bk][bt+4] = (double)x1.x; Bs[bk][bt+5] = (double)x1.y;
            Bs[bk][bt+6] = (double)x1.z; Bs[bk][bt+7] = (double)x1.w;
        }
        __syncthreads();
        #pragma unroll
        for (int k = 0; k < 16; ++k) {
            double ar[4], lr[4], br[8];
            #pragma unroll
            for (int h = 0; h < 2; ++h) {
                ar[2*h]   = Am[k][2*ty + 32*h];
                ar[2*h+1] = Am[k][2*ty + 32*h + 1];
                lr[2*h]   = Al[k][2*ty + 32*h];
                lr[2*h+1] = Al[k][2*ty + 32*h + 1];
            }
            #pragma unroll
            for (int h = 0; h < 4; ++h) {
                br[2*h]   = Bs[k][2*tx + 32*h];
                br[2*h+1] = Bs[k][2*tx + 32*h + 1];
            }
            #pragma unroll
            for (int i = 0; i < 4; ++i)
                #pragma unroll
                for (int j = 0; j < 8; ++j) {
                    am[i][j] = fma(ar[i], br[j], am[i][j]);
                    al[i][j] = fma(lr[i], br[j], al[i][j]);
                }
        }
        __syncthreads();
    }

    const int rows[4] = {2*ty, 2*ty+1, 2*ty+32, 2*ty+33};
    #pragma unroll
    for (int i = 0; i < 4; ++i) {
        const int f = m0 + rows[i];
        if (f >= 500) continue;
        const double bm = (double)B1[f];
        const double bl = (double)B1[500 + f];
        const size_t ebase = ((size_t)b * 500 + f) * 512 + t0;
        const size_t obase = ((size_t)b * 500 + f) * TC;
        #pragma unroll
        for (int j = 0; j < 8; ++j) {
            const int c = 2*tx + (j >> 1) * 32 + (j & 1);
            const double mu = fmax(am[i][j] + bm, 0.0);
            const double lv = fmax(al[i][j] + bl, 0.0);
            const double e  = (double)EPS[ebase + c];
            SAMP[obase + c] = mu + e * exp(0.5 * lv);
        }
    }
}

// ---------------------------------------------------------------------------
// iir2: exact sequential dual-exp, in-place on (32000 rows, TC). 64 rows per
// block staged through LDS in 64-col sub-chunks; (m,s) carried across chunks.
// ---------------------------------------------------------------------------
__global__ __launch_bounds__(256) void iir2_chunk(
    double* __restrict__ A,
    double* __restrict__ stM, double* __restrict__ stS, int first)
{
    __shared__ double tile[64][65];
    const int tid = threadIdx.x;
    const int r0 = blockIdx.x * 64;
    double m = 0.0, s = 0.0;
    if (tid < 64 && !first) { m = stM[r0 + tid]; s = stS[r0 + tid]; }

    for (int sub = 0; sub < TC / 64; ++sub) {
        #pragma unroll
        for (int q = 0; q < 8; ++q) {
            const int e2 = q * 256 + tid;
            const int r = e2 >> 5;
            const int c = (e2 & 31) * 2;
            const double2 v = *(const double2*)&A[(size_t)(r0 + r) * TC + sub * 64 + c];
            tile[r][c] = v.x; tile[r][c + 1] = v.y;
        }
        __syncthreads();
        if (tid < 64) {
            #pragma unroll
            for (int c = 0; c < 64; ++c) {
                const double x = tile[tid][c];
                m = EMD * m + x;
                s = ESD * s + x;
                tile[tid][c] = m - s;
            }
        }
        __syncthreads();
        #pragma unroll
        for (int q = 0; q < 8; ++q) {
            const int e2 = q * 256 + tid;
            const int r = e2 >> 5;
            const int c = (e2 & 31) * 2;
            double2 v; v.x = tile[r][c]; v.y = tile[r][c + 1];
            *(double2*)&A[(size_t)(r0 + r) * TC + sub * 64 + c] = v;
        }
        __syncthreads();
    }
    if (tid < 64) { stM[r0 + tid] = m; stS[r0 + tid] = s; }
}

// ---------------------------------------------------------------------------
// g2: wx2[tl,b,o] = sum_f a2[b,f,tl]*W2[o,f] + B2[o]; K=500 padded to 512.
// Micro 4tl x 8o; block tile 64tl x 128o. k-ascending single FMA chain.
// ---------------------------------------------------------------------------
__global__ __launch_bounds__(256) void g2_chunk(
    const double* __restrict__ A2,  // (64,500,TC)
    const float* __restrict__ W2,   // (500,500)
    const float* __restrict__ B2,   // (500)
    double* __restrict__ WX2)       // (TC,64,500)
{
    const int b   = blockIdx.z;
    const int o0  = blockIdx.y * 128;
    const int tl0 = blockIdx.x * 64;

    __shared__ double At[16][66];
    __shared__ double Wo[16][130];

    const int tid = threadIdx.x;
    const int tx = tid & 15;   // o dir
    const int ty = tid >> 4;   // tl dir

    double acc[4][8] = {};

    for (int k0 = 0; k0 < 512; k0 += 16) {
        {   // stage A: 16 f x 64 tl
            const int kk = tid >> 4;
            const int t4 = (tid & 15) * 4;
            const int f = k0 + kk;
            if (f < 500) {
                const double2 v0 = *(const double2*)&A2[((size_t)b * 500 + f) * TC + tl0 + t4];
                const double2 v1 = *(const double2*)&A2[((size_t)b * 500 + f) * TC + tl0 + t4 + 2];
                At[kk][t4+0] = v0.x; At[kk][t4+1] = v0.y;
                At[kk][t4+2] = v1.x; At[kk][t4+3] = v1.y;
            } else {
                At[kk][t4+0] = 0.0; At[kk][t4+1] = 0.0;
                At[kk][t4+2] = 0.0; At[kk][t4+3] = 0.0;
            }
        }
        {   // stage W: 16 f x 128 o
            const int oo = tid & 127;
            const int fc = (tid >> 7) * 8;
            int o = o0 + oo; if (o > 499) o = 499;
            const float* wp = &W2[(size_t)o * 500 + k0 + fc];
            if (k0 + fc + 7 < 500) {
                const float4 w0 = *(const float4*)wp;
                const float4 w1 = *(const float4*)(wp + 4);
                Wo[fc+0][oo] = (double)w0.x; Wo[fc+1][oo] = (double)w0.y;
                Wo[fc+2][oo] = (double)w0.z; Wo[fc+3][oo] = (double)w0.w;
                Wo[fc+4][oo] = (double)w1.x; Wo[fc+5][oo] = (double)w1.y;
                Wo[fc+6][oo] = (double)w1.z; Wo[fc+7][oo] = (double)w1.w;
            } else {
                #pragma unroll
                for (int c = 0; c < 8; ++c)
                    Wo[fc+c][oo] = (k0 + fc + c < 500) ? (double)wp[c] : 0.0;
            }
        }
        __syncthreads();
        #pragma unroll
        for (int k = 0; k < 16; ++k) {
            double ar[4], br[8];
            #pragma unroll
            for (int h = 0; h < 2; ++h) {
                ar[2*h]   = At[k][2*ty + 32*h];
                ar[2*h+1] = At[k][2*ty + 32*h + 1];
            }
            #pragma unroll
            for (int h = 0; h < 4; ++h) {
                br[2*h]   = Wo[k][2*tx + 32*h];
                br[2*h+1] = Wo[k][2*tx + 32*h + 1];
            }
            #pragma unroll
            for (int i = 0; i < 4; ++i)
                #pragma unroll
                for (int j = 0; j < 8; ++j)
                    acc[i][j] = fma(ar[i], br[j], acc[i][j]);
        }
        __syncthreads();
    }

    const int rows[4] = {2*ty, 2*ty+1, 2*ty+32, 2*ty+33};
    #pragma unroll
    for (int i = 0; i < 4; ++i) {
        const int tl = tl0 + rows[i];
        #pragma unroll
        for (int j = 0; j < 8; ++j) {
            const int o = o0 + 2*tx + (j >> 1) * 32 + (j & 1);
            if (o < 500)
                WX2[((size_t)tl * 64 + b) * 500 + o] = acc[i][j] + (double)B2[o];
        }
    }
}

// ---------------------------------------------------------------------------
// LIF2 + IIR3 fused, in-place on (TC, 32000); carries (v, sp, m, s).
// ---------------------------------------------------------------------------
__global__ __launch_bounds__(256) void lif2iir3_chunk(
    double* __restrict__ WX,
    double* __restrict__ stV, double* __restrict__ stSp,
    double* __restrict__ stM, double* __restrict__ stS, int first)
{
    const int idx = blockIdx.x * 256 + threadIdx.x;
    if (idx >= 32000) return;
    double v, sp, m, s;
    if (first) { v = 0.0; sp = 0.0; m = 0.0; s = 0.0; }
    else { v = stV[idx]; sp = stSp[idx]; m = stM[idx]; s = stS[idx]; }
    for (int tt = 0; tt < TC; ++tt) {
        const double cur = WX[(size_t)tt * 32000 + idx];
        v = EMD * v * (1.0 - sp) + cur;
        sp = (v >= 1.0) ? 1.0 : 0.0;
        m = EMD * m + sp;
        s = ESD * s + sp;
        WX[(size_t)tt * 32000 + idx] = m - s;
    }
    stV[idx] = v; stSp[idx] = sp; stM[idx] = m; stS[idx] = s;
}

// ---------------------------------------------------------------------------
// g3: one wave per R; lanes split K, 10 outputs tree-reduced via shfl_xor.
// Reads A3 exactly once (33 MB/chunk vs 330 MB for thread-per-(R,o)).
// ---------------------------------------------------------------------------
__global__ __launch_bounds__(256) void g3_chunk(
    const double* __restrict__ A3,  // (64*TC, 500)
    const float* __restrict__ W3,   // (10,500)
    const float* __restrict__ B3,   // (10)
    double* __restrict__ WX3)       // (64*TC, 10)
{
    __shared__ float w3s[5000];
    for (int i = threadIdx.x; i < 5000; i += 256) w3s[i] = W3[i];
    __syncthreads();

    const int lane = threadIdx.x & 63;
    const int R = blockIdx.x * 4 + (threadIdx.x >> 6);   // 0..8191
    const double* row = A3 + (size_t)R * 500;

    double p[10] = {};
    #pragma unroll
    for (int c = 0; c < 8; ++c) {
        const int i = c * 64 + lane;
        const int ii = (i < 500) ? i : 0;
        const double x = (i < 500) ? row[ii] : 0.0;
        #pragma unroll
        for (int o = 0; o < 10; ++o)
            p[o] = fma(x, (double)w3s[o * 500 + ii], p[o]);
    }
    #pragma unroll
    for (int off = 32; off; off >>= 1)
        #pragma unroll
        for (int o = 0; o < 10; ++o)
            p[o] += __shfl_xor(p[o], off, 64);
    if (lane < 10)
        WX3[(size_t)R * 10 + lane] = p[lane] + (double)B3[lane];
}

// ---------------------------------------------------------------------------
// lif3: (tt*640+idx) -> OUT[idx*512 + t0+tt]; carries (v, sp).
// ---------------------------------------------------------------------------
__global__ __launch_bounds__(256) void lif3_chunk(
    const double* __restrict__ WX3, float* __restrict__ OUT,
    double* __restrict__ stV, double* __restrict__ stSp, int first, int t0)
{
    const int idx = blockIdx.x * 256 + threadIdx.x;
    if (idx >= 640) return;
    double v = first ? 0.0 : stV[idx];
    double sp = first ? 0.0 : stSp[idx];
    for (int tt = 0; tt < TC; ++tt) {
        const double cur = WX3[(size_t)tt * 640 + idx];
        v = EMD * v * (1.0 - sp) + cur;
        sp = (v >= 1.0) ? 1.0 : 0.0;
        OUT[(size_t)idx * 512 + t0 + tt] = (float)sp;
    }
    stV[idx] = v; stSp[idx] = sp;
}

__global__ void sent_kernel(float* __restrict__ OUT, float v) { OUT[0] = v; }

// ---------------------------------------------------------------------------
extern "C" void kernel_launch(void* const* d_in, const int* in_sizes, int n_in,
                              void* d_out, int out_size, void* d_ws, size_t ws_size,
                              hipStream_t stream)
{
    float* OUT = (float*)d_out;

    const int expect[8] = {25690112, 16384000, 784000, 1000, 250000, 500, 5000, 10};
    int bad = -1;
    if (n_in != 8) bad = 0;
    else {
        for (int k = 0; k < 8; ++k)
            if (in_sizes[k] != expect[k]) { bad = 1 + k; break; }
        if (bad < 0 && out_size != 327680) bad = 9;
        if (bad < 0 && ws_size < (size_t)68000000) bad = 10;
    }
    if (bad >= 0) {
        sent_kernel<<<1, 1, 0, stream>>>(OUT, 4100.0f + bad);
        return;
    }

    const float* X   = (const float*)d_in[0];
    const float* EPS = (const float*)d_in[1];
    const float* W1  = (const float*)d_in[2];
    const float* B1  = (const float*)d_in[3];
    const float* W2  = (const float*)d_in[4];
    const float* B2  = (const float*)d_in[5];
    const float* W3  = (const float*)d_in[6];
    const float* B3  = (const float*)d_in[7];

    double* ws = (double*)d_ws;
    double* buf1  = ws;              // (64,500,TC)  4,096,000
    double* buf2  = ws + 4096000;    // (TC,64,500)  4,096,000
    double* buf4  = ws + 8192000;    // (64*TC,10)      81,920
    double* stM2  = ws + 8280000;
    double* stS2  = ws + 8312000;
    double* stV2  = ws + 8344000;
    double* stSp2 = ws + 8376000;
    double* stM3  = ws + 8408000;
    double* stS3  = ws + 8440000;
    double* stV3  = ws + 8472000;
    double* stSp3 = ws + 8473000;

    for (int tc = 0; tc < 512 / TC; ++tc) {
        const int t0 = tc * TC;
        const int first = (tc == 0) ? 1 : 0;
        g1_fused<<<dim3(1, 8, 64), 256, 0, stream>>>(X, W1, B1, EPS, buf1, t0);
        iir2_chunk<<<500, 256, 0, stream>>>(buf1, stM2, stS2, first);
        g2_chunk<<<dim3(2, 4, 64), 256, 0, stream>>>(buf1, W2, B2, buf2);
        lif2iir3_chunk<<<125, 256, 0, stream>>>(buf2, stV2, stSp2, stM3, stS3, first);
        g3_chunk<<<2048, 256, 0, stream>>>(buf2, W3, B3, buf4);
        lif3_chunk<<<3, 256, 0, stream>>>(buf4, OUT, stV3, stSp3, first, t0);
    }
}